// Round 10
// baseline (271.501 us; speedup 1.0000x reference)
//
#include <hip/hip_runtime.h>

#define HW   128
#define OHW  256
#define G0n  64
#define HID  256
#define NOUT 1728
#define NB   4

typedef __attribute__((ext_vector_type(8))) short bf16x8;
typedef __attribute__((ext_vector_type(4))) float f32x4;
typedef __attribute__((ext_vector_type(4))) unsigned int u32x4;
typedef __attribute__((ext_vector_type(2))) unsigned int u32x2;

__device__ __forceinline__ unsigned short f2bf(float f) {
    unsigned int u = __builtin_bit_cast(unsigned int, f);
    u += 0x7fffu + ((u >> 16) & 1u);
    return (unsigned short)(u >> 16);
}
__device__ __forceinline__ float bflo(unsigned int d) {
    return __builtin_bit_cast(float, d << 16);
}
__device__ __forceinline__ float bfhi(unsigned int d) {
    return __builtin_bit_cast(float, d & 0xffff0000u);
}

__device__ __forceinline__ void barrier_ldsonly() {
    __builtin_amdgcn_sched_barrier(0);
    asm volatile("s_waitcnt lgkmcnt(0)" ::: "memory");
    __builtin_amdgcn_s_barrier();
    __builtin_amdgcn_sched_barrier(0);
}

// ---------------- Kernel 0: w2 [256][1728] f32 -> w2t [1728][256] bf16 (LDS tiled) ----
__global__ __launch_bounds__(256) void prep_w2t(const float* __restrict__ w2,
                                                unsigned short* __restrict__ w2t) {
    __shared__ float t[64][65];
    int kb = blockIdx.x & 3, cb = blockIdx.x >> 2;
    int lc = threadIdx.x & 63, lr = threadIdx.x >> 6;
    #pragma unroll
    for (int i = 0; i < 16; ++i) {
        int kk = lr + i * 4;
        t[kk][lc] = w2[(kb * 64 + kk) * NOUT + cb * 64 + lc];
    }
    __syncthreads();
    #pragma unroll
    for (int i = 0; i < 16; ++i) {
        int cc = lr + i * 4;
        w2t[(cb * 64 + cc) * 256 + kb * 64 + lc] = f2bf(t[lc][cc]);
    }
}

// ---------------- Kernel 1: 5x5 SAME conv + bias + ReLU, 4 outputs/thread ----------------
__global__ __launch_bounds__(256) void conv5_relu_kernel(
    const float* __restrict__ x, const float* __restrict__ cw,
    const float* __restrict__ cb, float* __restrict__ feat)
{
    int idx = blockIdx.x * 256 + threadIdx.x;
    int w4 = (idx & 31) * 4;
    int h  = (idx >> 5) & 127;
    int g  = (idx >> 12) & 63;
    int n  = idx >> 18;
    float bv = cb[g];
    float a[4] = {bv, bv, bv, bv};
    const float* wp = cw + g * 75;
    #pragma unroll
    for (int ci = 0; ci < 3; ++ci) {
        const float* xr = x + (n * 3 + ci) * (HW * HW);
        #pragma unroll
        for (int ki = 0; ki < 5; ++ki) {
            int hh = h + ki - 2;
            if (hh < 0 || hh >= HW) continue;
            const float* row = xr + hh * HW;
            float f[8];
            if (w4 != 0 && w4 != 124) {
                float2 u0 = *(const float2*)(row + w4 - 2);
                float2 u1 = *(const float2*)(row + w4);
                float2 u2 = *(const float2*)(row + w4 + 2);
                float2 u3 = *(const float2*)(row + w4 + 4);
                f[0] = u0.x; f[1] = u0.y; f[2] = u1.x; f[3] = u1.y;
                f[4] = u2.x; f[5] = u2.y; f[6] = u3.x; f[7] = u3.y;
            } else {
                #pragma unroll
                for (int j = 0; j < 8; ++j) {
                    int ww = w4 - 2 + j;
                    f[j] = (ww >= 0 && ww < HW) ? row[ww] : 0.0f;
                }
            }
            float wt[5];
            #pragma unroll
            for (int kj = 0; kj < 5; ++kj) wt[kj] = wp[ci * 25 + ki * 5 + kj];
            #pragma unroll
            for (int j = 0; j < 4; ++j)
                #pragma unroll
                for (int kj = 0; kj < 5; ++kj)
                    a[j] = fmaf(f[j + kj], wt[kj], a[j]);
        }
    }
    float4 o;
    o.x = fmaxf(a[0], 0.f); o.y = fmaxf(a[1], 0.f);
    o.z = fmaxf(a[2], 0.f); o.w = fmaxf(a[3], 0.f);
    *(float4*)&feat[((n * G0n + g) * HW + h) * HW + w4] = o;
}

// ---------------- Kernel 2a: MFMA GEMM, M=128/block, A in LDS, 2-deep B prefetch ------
// 256 threads (4 waves = 4 N-quarters). Per k-step: 3 B-loads feed 24 MFMAs.
__global__ __launch_bounds__(256, 1) void gemm_lw(
    const unsigned short* __restrict__ w2t, const float* __restrict__ pos,
    const float* __restrict__ w1, const float* __restrict__ b1,
    const float* __restrict__ b2, unsigned short* __restrict__ lw)
{
    __shared__ __align__(16) unsigned short A[128 * 260];    // 66560 B, hidden acts
    __shared__ __align__(16) unsigned short CS[128 * 200];   // 51200 B, C store-stage

    const int tid = threadIdx.x;
    const int b = blockIdx.x;

    // ---- hidden = relu(pos @ w1 + b1) -> A[px2][256]; 128 k per thread ----
    {
        int px2 = tid >> 1, q = tid & 1;
        int cb = 2 * b + (px2 >> 6);
        int px64 = px2 & 63;
        int bx = cb & 31, by = cb >> 5;
        int rr = (by * 8 + (px64 >> 3)) * OHW + (bx * 8 + (px64 & 7));
        float p0 = pos[rr * 3 + 0], p1 = pos[rr * 3 + 1], p2 = pos[rr * 3 + 2];
        #pragma unroll
        for (int j = 0; j < 32; ++j) {
            int k0 = q * 128 + j * 4;
            float4 wa = *(const float4*)&w1[k0];
            float4 wb = *(const float4*)&w1[HID + k0];
            float4 wc = *(const float4*)&w1[2 * HID + k0];
            float4 bb = *(const float4*)&b1[k0];
            unsigned short h0s = f2bf(fmaxf(fmaf(p0, wa.x, fmaf(p1, wb.x, fmaf(p2, wc.x, bb.x))), 0.f));
            unsigned short h1s = f2bf(fmaxf(fmaf(p0, wa.y, fmaf(p1, wb.y, fmaf(p2, wc.y, bb.y))), 0.f));
            unsigned short h2s = f2bf(fmaxf(fmaf(p0, wa.z, fmaf(p1, wb.z, fmaf(p2, wc.z, bb.z))), 0.f));
            unsigned short h3s = f2bf(fmaxf(fmaf(p0, wa.w, fmaf(p1, wb.w, fmaf(p2, wc.w, bb.w))), 0.f));
            u32x2 pk;
            pk.x = (unsigned)h0s | ((unsigned)h1s << 16);
            pk.y = (unsigned)h2s | ((unsigned)h3s << 16);
            *(u32x2*)&A[px2 * 260 + k0] = pk;
        }
    }
    __syncthreads();

    const int lane = tid & 63, nq = tid >> 6;
    const int cl = lane & 15, hi = lane >> 4;
    const size_t rowbase = (size_t)b * 128;
    const int srow = tid >> 2, sq = tid & 3;

    for (int ch = 0; ch < 9; ++ch) {
        f32x4 acc[8][3];
        #pragma unroll
        for (int m = 0; m < 8; ++m)
            #pragma unroll
            for (int j = 0; j < 3; ++j)
                acc[m][j] = (f32x4){0.f, 0.f, 0.f, 0.f};

        const unsigned short* wp = w2t + ((size_t)(ch * 192 + nq * 48 + cl)) * 256 + hi * 8;
        bf16x8 bfr[3][3];          // 2-deep rotating B prefetch
        #pragma unroll
        for (int j = 0; j < 3; ++j) bfr[0][j] = *(const bf16x8*)(wp + j * 4096);
        #pragma unroll
        for (int j = 0; j < 3; ++j) bfr[1][j] = *(const bf16x8*)(wp + j * 4096 + 32);
        bf16x8 afr[2][8];
        #pragma unroll
        for (int m = 0; m < 8; ++m)
            afr[0][m] = *(const bf16x8*)&A[(m * 16 + cl) * 260 + hi * 8];

        #pragma unroll
        for (int ks = 0; ks < 8; ++ks) {
            // prefetch A (ks+1) and B (ks+2)
            if (ks < 7) {
                #pragma unroll
                for (int m = 0; m < 8; ++m)
                    afr[(ks + 1) & 1][m] =
                        *(const bf16x8*)&A[(m * 16 + cl) * 260 + (ks + 1) * 32 + hi * 8];
            }
            if (ks < 6) {
                #pragma unroll
                for (int j = 0; j < 3; ++j)
                    bfr[(ks + 2) % 3][j] = *(const bf16x8*)(wp + j * 4096 + (ks + 2) * 32);
            }
            #pragma unroll
            for (int m = 0; m < 8; ++m)
                #pragma unroll
                for (int j = 0; j < 3; ++j)
                    acc[m][j] = __builtin_amdgcn_mfma_f32_16x16x32_bf16(
                        afr[ks & 1][m], bfr[ks % 3][j], acc[m][j], 0, 0, 0);
        }

        // barrier A: prev chunk's store-phase LDS reads done (lgkm only)
        barrier_ldsonly();
        #pragma unroll
        for (int j = 0; j < 3; ++j) {
            int lcol = nq * 48 + j * 16 + cl;
            float bv = b2[ch * 192 + lcol];
            #pragma unroll
            for (int m = 0; m < 8; ++m)
                #pragma unroll
                for (int r = 0; r < 4; ++r)
                    CS[(m * 16 + hi * 4 + r) * 200 + lcol] = f2bf(acc[m][j][r] + bv);
        }
        // barrier B: scatter visible to store phase (lgkm only)
        barrier_ldsonly();
        #pragma unroll
        for (int r2 = 0; r2 < 128; r2 += 64) {
            unsigned short* dst = lw + (rowbase + srow + r2) * NOUT + ch * 192;
            #pragma unroll
            for (int s = 0; s < 6; ++s) {
                int off = (sq + s * 4) * 8;
                *(u32x4*)(dst + off) = *(const u32x4*)&CS[(srow + r2) * 200 + off];
            }
        }
    }
}

// ---------------- Kernel 2b: einsum + mean-shift, lw chunks staged through LDS --------
// 64 px/block. Stage chunk [64][192] coalesced -> repack to [px][kt*4+c] -> t3 loop.
__global__ __launch_bounds__(256) void einsum_out(
    const float* __restrict__ feat, const unsigned short* __restrict__ lw,
    float* __restrict__ out)
{
    __shared__ __align__(8) unsigned short FT[64 * 6 * 4 * 6];   // 18432 B
    __shared__ __align__(16) unsigned short LW[64 * 260];        // 33280 B

    const int tid = threadIdx.x;
    const int bx = blockIdx.x & 31, by = blockIdx.x >> 5;
    const int oy0 = by * 8, ox0 = bx * 8;
    const int h0 = by * 4,  w0 = bx * 4;

    for (int i = tid; i < 64 * 6 * 4 * 6; i += 256) {
        int c = i % 6;
        int t = i / 6;
        int n = t & 3;
        t >>= 2;
        int r  = t % 6;
        int ci = t / 6;
        int gh = h0 - 1 + r, gw = w0 - 1 + c;
        float v = 0.0f;
        if (gh >= 0 && gh < HW && gw >= 0 && gw < HW)
            v = feat[((n * G0n + ci) * HW + gh) * HW + gw];
        FT[i] = f2bf(v);
    }

    const int row = tid >> 2, q = tid & 3;        // staging roles
    const int epx = tid >> 2, en = tid & 3;       // compute roles
    const int iy = (epx >> 3) >> 1;
    const int ix = (epx & 7) >> 1;
    const bool podd = (ix & 1) != 0;
    const int ixa = ix & ~1;
    float o0 = 0.f, o1 = 0.f, o2 = 0.f;

    for (int ch = 0; ch < 9; ++ch) {
        __syncthreads();   // FT staged (ch=0) / prev compute reads of LW done
        // ---- stage lw chunk: 6 coalesced b128 loads -> repack to [row][kt*4+c] ----
        {
            const unsigned short* src =
                lw + ((size_t)blockIdx.x * 64 + row) * NOUT + ch * 192 + q * 48;
            u32x4 in4[6];
            #pragma unroll
            for (int t = 0; t < 6; ++t) in4[t] = *(const u32x4*)(src + t * 8);
            const unsigned* in = (const unsigned*)in4;       // 24 u32 = 48 shorts
            unsigned short* dstl = LW + row * 260 + q * 64;  // 16 kt * 4 shorts
            #pragma unroll
            for (int l = 0; l < 16; ++l) {
                int s = 3 * l;
                unsigned lo, hi2;
                if ((s & 1) == 0) {
                    lo  = in[s >> 1];
                    hi2 = in[(s >> 1) + 1];
                } else {
                    lo  = (in[s >> 1] >> 16) | (in[(s >> 1) + 1] << 16);
                    hi2 = in[(s >> 1) + 1] >> 16;
                }
                u32x2 pk; pk.x = lo; pk.y = hi2;
                *(u32x2*)(dstl + l * 4) = pk;
            }
        }
        __syncthreads();

        // ---- einsum partial over this chunk's 64 kt (t3 loop, r3-proven) ----
        const char* lwp = (const char*)LW + epx * 520;
        int k0 = ch * 64;
        int t3a = k0 / 3;
        int t3b = (k0 + 63) / 3;
        auto do_t3 = [&](int t3, bool guard) {
            int ci = t3 / 3;
            int di = t3 - ci * 3;
            int rb = ((ci * 6 + iy + di) * 4 + en) * 6 + ixa;
            unsigned u0 = *(const unsigned*)&FT[rb];
            unsigned u1 = *(const unsigned*)&FT[rb + 2];
            float f0 = podd ? bfhi(u0) : bflo(u0);
            float f1 = podd ? bflo(u1) : bfhi(u0);
            float f2 = podd ? bfhi(u1) : bflo(u1);
            int ktb = 3 * t3 - k0;
            #pragma unroll
            for (int dj = 0; dj < 3; ++dj) {
                int kt = ktb + dj;
                float fvv = dj == 0 ? f0 : (dj == 1 ? f1 : f2);
                if (guard) {
                    fvv = ((unsigned)kt < 64u) ? fvv : 0.0f;
                    kt = kt < 0 ? 0 : (kt > 63 ? 63 : kt);
                }
                u32x2 d = *(const u32x2*)(lwp + (unsigned)(kt * 8));
                o0 = fmaf(fvv, bflo(d.x), o0);
                o1 = fmaf(fvv, bfhi(d.x), o1);
                o2 = fmaf(fvv, bflo(d.y), o2);
            }
        };
        do_t3(t3a, true);
        for (int t3 = t3a + 1; t3 < t3b; ++t3) do_t3(t3, false);
        do_t3(t3b, true);
    }

    int oy = oy0 + (epx >> 3), ox = ox0 + (epx & 7);
    out[((en * 3 + 0) * OHW + oy) * OHW + ox] = o0 + 0.4488f * 255.0f;
    out[((en * 3 + 1) * OHW + oy) * OHW + ox] = o1 + 0.4371f * 255.0f;
    out[((en * 3 + 2) * OHW + oy) * OHW + ox] = o2 + 0.4040f * 255.0f;
}

extern "C" void kernel_launch(void* const* d_in, const int* in_sizes, int n_in,
                              void* d_out, int out_size, void* d_ws, size_t ws_size,
                              hipStream_t stream) {
    (void)in_sizes; (void)n_in; (void)out_size; (void)ws_size;
    const float* x      = (const float*)d_in[0];
    const float* posm   = (const float*)d_in[1];
    const float* conv_w = (const float*)d_in[2];
    const float* conv_b = (const float*)d_in[3];
    const float* w1     = (const float*)d_in[4];
    const float* b1     = (const float*)d_in[5];
    const float* w2     = (const float*)d_in[6];
    const float* b2     = (const float*)d_in[7];
    float* out = (float*)d_out;

    unsigned short* w2t = (unsigned short*)d_ws;                     // 884,736 B
    float* feat = (float*)((char*)d_ws + 884736);                    // 16,777,216 B
    const size_t lw_off = 884736u + 16777216u;                       // 17,661,952
    unsigned short* lwbuf = (unsigned short*)((char*)d_ws + lw_off); // 226,492,416 B

    prep_w2t<<<108, 256, 0, stream>>>(w2, w2t);
    conv5_relu_kernel<<<(NB * G0n * HW * 32) / 256, 256, 0, stream>>>(x, conv_w, conv_b, feat);
    gemm_lw<<<512, 256, 0, stream>>>(w2t, posm, w1, b1, b2, lwbuf);
    einsum_out<<<1024, 256, 0, stream>>>(feat, lwbuf, out);
}